// Round 3
// baseline (1173.676 us; speedup 1.0000x reference)
//
#include <hip/hip_runtime.h>
#include <math.h>

#define NFFT 512
#define HOP 128
#define NBINS 257
#define ROW 1028          // 4*257
#define CHUNK 1024
#define NBLK_SUM 64

// ---------- prep: sparse filterbank spans + chunk-0 pcen init ----------
__global__ void k_prep(const float* __restrict__ fb, int* __restrict__ lohi,
                       float* __restrict__ minit) {
  int t = threadIdx.x;
  for (int m = t; m < NBINS; m += 256) {
    int lo = 0, hi = -1;
    for (int f = 0; f < NBINS; ++f) {
      if (fb[f * NBINS + m] != 0.0f) { if (hi < 0) lo = f; hi = f; }
    }
    lohi[m] = lo;
    lohi[NBINS + m] = hi;
    minit[m] = 0.0f;  // chunk 0 starts from m_{-1} = 0  (=> m_0 = s*x_0)
  }
}

// ---------- per-frame 512-pt FFT + outputs ----------
// out layout per frame: [log_mag(257), mel(257, staged), sin(257), cos(257)]
__global__ __launch_bounds__(256) void k_fft(
    const float* __restrict__ audio, const float* __restrict__ fb,
    const int* __restrict__ lohi, float* __restrict__ out, int T) {
  __shared__ float2 bufA[NFFT];
  __shared__ float2 bufB[NFFT];
  __shared__ float2 tw[NFFT];
  __shared__ float mspec[NBINS];

  const int t = threadIdx.x;
  const int fr = blockIdx.x;

  // twiddle table tw[i] = e^{-2*pi*i* i /512}
  for (int i = t; i < NFFT; i += 256) {
    float ang = (float)(-6.283185307179586 / (double)NFFT) * (float)i;
    float s, c;
    sincosf(ang, &s, &c);
    tw[i] = make_float2(c, s);
  }
  // load frame with reflect padding
  int start = fr * HOP - NFFT / 2;
  for (int i = t; i < NFFT; i += 256) {
    int q = start + i;
    if (q < 0) q = -q;
    if (q >= T) q = 2 * T - 2 - q;
    bufA[i] = make_float2(audio[q], 0.0f);
  }
  __syncthreads();

  // 9-stage Stockham DIF, natural order in/out (verified by hand at N=4, N=8)
  float2* x = bufA;
  float2* y = bufB;
  for (int s = 0; s < 9; ++s) {
    int m = 1 << s;
    int jm = t & ~(m - 1);
    float2 c0 = x[t];
    float2 c1 = x[t + 256];
    float2 w = tw[jm];
    float2 su = make_float2(c0.x + c1.x, c0.y + c1.y);
    float2 di = make_float2(c0.x - c1.x, c0.y - c1.y);
    float2 wd = make_float2(w.x * di.x - w.y * di.y, w.x * di.y + w.y * di.x);
    y[t + jm] = su;
    y[t + jm + m] = wd;
    __syncthreads();
    float2* tmp = x; x = y; y = tmp;
  }

  long ob = (long)fr * ROW;
  for (int k = t; k < NBINS; k += 256) {
    float2 z = x[k];
    float mag, sv, cv;
    if (k == 0 || k == 256) {
      // Structural: z.y is EXACTLY 0 here (bins 0/256 route through
      // twiddle-free butterflies only). The f32 reference computes
      // sin(atan2(+0, re)) = sin(pi_f32) = -8.742278e-8 when re<0 — NOT 0.
      // F.normalize then scales that column to -1/sqrt(N_neg) ~ -7.29e-3,
      // so we must emit the same tiny values for the norm to match.
      mag = fabsf(z.x);
      sv = sinf(atan2f(0.0f, z.x));
      cv = copysignf(1.0f, z.x);
    } else {
      mag = sqrtf(z.x * z.x + z.y * z.y);
      float inv = (mag > 0.0f) ? 1.0f / mag : 0.0f;
      sv = (mag > 0.0f) ? z.y * inv : 0.0f;   // sin(angle) = im/|z|
      cv = (mag > 0.0f) ? z.x * inv : 1.0f;   // cos(angle) = re/|z|
    }
    out[ob + k] = logf(mag + 1e-9f);
    out[ob + 2 * NBINS + k] = sv;
    out[ob + 3 * NBINS + k] = cv;
    // hann spectrum via 3-tap stencil on full rect spectrum
    float2 zm = x[(k + NFFT - 1) & (NFFT - 1)];
    float2 zp = x[(k + 1) & (NFFT - 1)];
    float hr = 0.5f * z.x - 0.25f * (zm.x + zp.x);
    float hi = 0.5f * z.y - 0.25f * (zm.y + zp.y);
    mspec[k] = hr * hr + hi * hi;
  }
  __syncthreads();

  // sparse mel: stage into ch1
  for (int m = t; m < NBINS; m += 256) {
    int lo = lohi[m], hi = lohi[NBINS + m];
    float acc = 0.0f;
    for (int f = lo; f <= hi; ++f) acc = fmaf(mspec[f], fb[f * NBINS + m], acc);
    out[ob + NBINS + m] = acc;
  }
}

// ---------- pcen warm-up: incoming state per chunk ----------
__global__ void k_pcen_init(const float* __restrict__ out,
                            float* __restrict__ minit, int nframes) {
  int m = threadIdx.x;
  if (m >= NBINS) return;
  int c = blockIdx.x + 1;  // chunks 1..
  int F0 = c * CHUNK;
  const float SS = 0.025f, OMS = 1.0f - SS;
  float mm = 0.0f;  // (1-s)^1024 ~ 5.6e-12: older state is below f32 eps
  for (int tf = F0 - CHUNK; tf < F0; ++tf) {
    float xv = out[(long)tf * ROW + NBINS + m];
    mm = OMS * mm + SS * xv;
  }
  minit[c * NBINS + m] = mm;
}

// ---------- pcen: scan own chunk, overwrite mel with pcen ----------
__global__ void k_pcen(float* __restrict__ out, const float* __restrict__ minit,
                       int nframes) {
  int m = threadIdx.x;
  if (m >= NBINS) return;
  int c = blockIdx.x;
  int F0 = c * CHUNK;
  int end = min(F0 + CHUNK, nframes);
  const float SS = 0.025f, OMS = 1.0f - SS;
  const float SQ2 = sqrtf(2.0f);
  float mm = minit[c * NBINS + m];
  for (int tf = F0; tf < end; ++tf) {
    long idx = (long)tf * ROW + NBINS + m;
    float xv = out[idx];
    mm = OMS * mm + SS * xv;
    float den = expf(0.98f * logf(mm + 1e-6f));
    out[idx] = sqrtf(xv / den + 2.0f) - SQ2;
  }
}

// ---------- column sum-of-squares partials (deterministic, no atomics) ----------
__global__ __launch_bounds__(256) void k_sumsq(const float* __restrict__ out,
                                               float* __restrict__ part,
                                               int nframes) {
  int b = blockIdx.x, t = threadIdx.x;
  int per = (nframes + NBLK_SUM - 1) / NBLK_SUM;
  int f0 = b * per;
  int f1 = min(f0 + per, nframes);
  float acc[5] = {0.f, 0.f, 0.f, 0.f, 0.f};
  for (int f = f0; f < f1; ++f) {
    long base = (long)f * ROW;
#pragma unroll
    for (int j = 0; j < 4; ++j) {
      float v = out[base + t + 256 * j];
      acc[j] = fmaf(v, v, acc[j]);
    }
    if (t < ROW - 1024) {
      float v = out[base + 1024 + t];
      acc[4] = fmaf(v, v, acc[4]);
    }
  }
#pragma unroll
  for (int j = 0; j < 4; ++j) part[(long)b * ROW + t + 256 * j] = acc[j];
  if (t < ROW - 1024) part[(long)b * ROW + 1024 + t] = acc[4];
}

// ---------- finalize norms ----------
__global__ void k_norm(const float* __restrict__ part, float* __restrict__ invn) {
  int t = threadIdx.x;
  for (int col = t; col < ROW; col += 256) {
    float s = 0.0f;
    for (int b = 0; b < NBLK_SUM; ++b) s += part[(long)b * ROW + col];
    float nrm = fmaxf(sqrtf(s), 1e-12f);
    invn[col] = 1.0f / nrm;
  }
}

// ---------- scale pass ----------
__global__ __launch_bounds__(256) void k_scale(float4* __restrict__ out4,
                                               const float* __restrict__ invn,
                                               long n4) {
  __shared__ float inv[ROW];
  for (int i = threadIdx.x; i < ROW; i += 256) inv[i] = invn[i];
  __syncthreads();
  long stride = (long)gridDim.x * 256;
  for (long i = (long)blockIdx.x * 256 + threadIdx.x; i < n4; i += stride) {
    float4 v = out4[i];
    int col = (int)((i * 4) % ROW);
    v.x *= inv[col];
    v.y *= inv[col + 1];
    v.z *= inv[col + 2];
    v.w *= inv[col + 3];
    out4[i] = v;
  }
}

extern "C" void kernel_launch(void* const* d_in, const int* in_sizes, int n_in,
                              void* d_out, int out_size, void* d_ws, size_t ws_size,
                              hipStream_t stream) {
  const float* audio = (const float*)d_in[0];
  const float* fb = (const float*)d_in[1];
  int T = in_sizes[0];
  int nframes = 1 + T / HOP;  // center=True, pad = NFFT/2 both sides
  float* out = (float*)d_out;

  // workspace layout (all f32 unless noted): part[64*1028] | invn[1028] | minit[chunks*257] | lohi[2*257] (int)
  float* part = (float*)d_ws;
  float* invn = part + (long)NBLK_SUM * ROW;
  int chunks = (nframes + CHUNK - 1) / CHUNK;
  float* minit = invn + ROW;
  int* lohi = (int*)(minit + (long)chunks * NBINS);

  k_prep<<<1, 256, 0, stream>>>(fb, lohi, minit);
  k_fft<<<nframes, 256, 0, stream>>>(audio, fb, lohi, out, T);
  if (chunks > 1) k_pcen_init<<<chunks - 1, 320, 0, stream>>>(out, minit, nframes);
  k_pcen<<<chunks, 320, 0, stream>>>(out, minit, nframes);
  k_sumsq<<<NBLK_SUM, 256, 0, stream>>>(out, part, nframes);
  k_norm<<<1, 256, 0, stream>>>(part, invn);
  long n4 = (long)nframes * ROW / 4;
  k_scale<<<2048, 256, 0, stream>>>((float4*)out, invn, n4);
}

// Round 4
// 579.258 us; speedup vs baseline: 2.0262x; 2.0262x over previous
//
#include <hip/hip_runtime.h>
#include <math.h>

#define NFFT 512
#define HOP 128
#define NBINS 257
#define ROW 1028          // 4*257
#define CHUNK 128
#define WARM 512          // (0.975)^512 = 2.4e-6: older state negligible
#define NBLK_SUM 64

// ---------- prep: sparse filterbank spans ----------
__global__ void k_prep(const float* __restrict__ fb, int* __restrict__ lohi) {
  int t = threadIdx.x;
  for (int m = t; m < NBINS; m += 256) {
    int lo = 0, hi = -1;
    for (int f = 0; f < NBINS; ++f) {
      if (fb[f * NBINS + m] != 0.0f) { if (hi < 0) lo = f; hi = f; }
    }
    lohi[m] = lo;
    lohi[NBINS + m] = hi;
  }
}

// ---------- per-frame 512-pt FFT + outputs ----------
// out layout per frame: [log_mag(257), mel(257, staged), sin(257), cos(257)]
__global__ __launch_bounds__(256) void k_fft(
    const float* __restrict__ audio, const float* __restrict__ fb,
    const int* __restrict__ lohi, float* __restrict__ out, int T) {
  __shared__ float2 bufA[NFFT];
  __shared__ float2 bufB[NFFT];
  __shared__ float2 tw[NFFT];
  __shared__ float mspec[NBINS];

  const int t = threadIdx.x;
  const int fr = blockIdx.x;

  // twiddle table tw[i] = e^{-2*pi*i* i /512}
  for (int i = t; i < NFFT; i += 256) {
    float ang = (float)(-6.283185307179586 / (double)NFFT) * (float)i;
    float s, c;
    sincosf(ang, &s, &c);
    tw[i] = make_float2(c, s);
  }
  // load frame with reflect padding
  int start = fr * HOP - NFFT / 2;
  for (int i = t; i < NFFT; i += 256) {
    int q = start + i;
    if (q < 0) q = -q;
    if (q >= T) q = 2 * T - 2 - q;
    bufA[i] = make_float2(audio[q], 0.0f);
  }
  __syncthreads();

  // 9-stage Stockham DIF, natural order in/out (verified by hand at N=4, N=8)
  float2* x = bufA;
  float2* y = bufB;
  for (int s = 0; s < 9; ++s) {
    int m = 1 << s;
    int jm = t & ~(m - 1);
    float2 c0 = x[t];
    float2 c1 = x[t + 256];
    float2 w = tw[jm];
    float2 su = make_float2(c0.x + c1.x, c0.y + c1.y);
    float2 di = make_float2(c0.x - c1.x, c0.y - c1.y);
    float2 wd = make_float2(w.x * di.x - w.y * di.y, w.x * di.y + w.y * di.x);
    y[t + jm] = su;
    y[t + jm + m] = wd;
    __syncthreads();
    float2* tmp = x; x = y; y = tmp;
  }

  long ob = (long)fr * ROW;
  for (int k = t; k < NBINS; k += 256) {
    float2 z = x[k];
    float mag, sv, cv;
    if (k == 0 || k == 256) {
      // Structural: z.y is EXACTLY 0 here (bins 0/256 route through
      // twiddle-free butterflies only). The f32 reference computes
      // sin(atan2(+0, re)) = sin(pi_f32) = -8.742278e-8 when re<0 — NOT 0.
      // F.normalize then scales that column to -1/sqrt(N_neg) ~ -7.29e-3,
      // so we must emit the same tiny values for the norm to match.
      mag = fabsf(z.x);
      sv = sinf(atan2f(0.0f, z.x));
      cv = copysignf(1.0f, z.x);
    } else {
      mag = sqrtf(z.x * z.x + z.y * z.y);
      float inv = (mag > 0.0f) ? 1.0f / mag : 0.0f;
      sv = (mag > 0.0f) ? z.y * inv : 0.0f;   // sin(angle) = im/|z|
      cv = (mag > 0.0f) ? z.x * inv : 1.0f;   // cos(angle) = re/|z|
    }
    out[ob + k] = logf(mag + 1e-9f);
    out[ob + 2 * NBINS + k] = sv;
    out[ob + 3 * NBINS + k] = cv;
    // hann spectrum via 3-tap stencil on full rect spectrum
    float2 zm = x[(k + NFFT - 1) & (NFFT - 1)];
    float2 zp = x[(k + 1) & (NFFT - 1)];
    float hr = 0.5f * z.x - 0.25f * (zm.x + zp.x);
    float hi = 0.5f * z.y - 0.25f * (zm.y + zp.y);
    mspec[k] = hr * hr + hi * hi;
  }
  __syncthreads();

  // sparse mel: stage into ch1
  for (int m = t; m < NBINS; m += 256) {
    int lo = lohi[m], hi = lohi[NBINS + m];
    float acc = 0.0f;
    for (int f = lo; f <= hi; ++f) acc = fmaf(mspec[f], fb[f * NBINS + m], acc);
    out[ob + NBINS + m] = acc;
  }
}

// ---------- fused pcen: warm-up (512 frames, from 0 for early chunks) + scan ----------
// Latency-bound before: 1 dependent-looking load per frame, 1000cy each.
// Now: 16 loads batched per iteration (fully unrolled -> registers, rule #20),
// 293 blocks for TLP.
__global__ __launch_bounds__(320) void k_pcen(float* __restrict__ out, int nframes) {
  int m = threadIdx.x;
  if (m >= NBINS) return;
  int c = blockIdx.x;
  int F0 = c * CHUNK;
  int end = min(F0 + CHUNK, nframes);
  const float SS = 0.025f, OMS = 1.0f - SS;
  const float SQ2 = sqrtf(2.0f);
  float mm = 0.0f;
  int tf = F0 - WARM;
  if (tf < 0) tf = 0;   // chunks 0..3: exact from frame 0
  // warm-up, batched 16
  for (; tf + 16 <= F0; tf += 16) {
    float xs[16];
#pragma unroll
    for (int j = 0; j < 16; ++j) xs[j] = out[(long)(tf + j) * ROW + NBINS + m];
#pragma unroll
    for (int j = 0; j < 16; ++j) mm = OMS * mm + SS * xs[j];
  }
  for (; tf < F0; ++tf) mm = OMS * mm + SS * out[(long)tf * ROW + NBINS + m];
  // scan + rewrite, batched 16
  tf = F0;
  for (; tf + 16 <= end; tf += 16) {
    float xs[16], ys[16];
#pragma unroll
    for (int j = 0; j < 16; ++j) xs[j] = out[(long)(tf + j) * ROW + NBINS + m];
#pragma unroll
    for (int j = 0; j < 16; ++j) {
      mm = OMS * mm + SS * xs[j];
      float den = expf(0.98f * logf(mm + 1e-6f));
      ys[j] = sqrtf(xs[j] / den + 2.0f) - SQ2;
    }
#pragma unroll
    for (int j = 0; j < 16; ++j) out[(long)(tf + j) * ROW + NBINS + m] = ys[j];
  }
  for (; tf < end; ++tf) {
    long idx = (long)tf * ROW + NBINS + m;
    float xv = out[idx];
    mm = OMS * mm + SS * xv;
    float den = expf(0.98f * logf(mm + 1e-6f));
    out[idx] = sqrtf(xv / den + 2.0f) - SQ2;
  }
}

// ---------- column sum-of-squares partials (deterministic, no atomics) ----------
__global__ __launch_bounds__(256) void k_sumsq(const float* __restrict__ out,
                                               float* __restrict__ part,
                                               int nframes) {
  int b = blockIdx.x, t = threadIdx.x;
  int per = (nframes + NBLK_SUM - 1) / NBLK_SUM;
  int f0 = b * per;
  int f1 = min(f0 + per, nframes);
  float acc[5] = {0.f, 0.f, 0.f, 0.f, 0.f};
  for (int f = f0; f < f1; ++f) {
    long base = (long)f * ROW;
#pragma unroll
    for (int j = 0; j < 4; ++j) {
      float v = out[base + t + 256 * j];
      acc[j] = fmaf(v, v, acc[j]);
    }
    if (t < ROW - 1024) {
      float v = out[base + 1024 + t];
      acc[4] = fmaf(v, v, acc[4]);
    }
  }
#pragma unroll
  for (int j = 0; j < 4; ++j) part[(long)b * ROW + t + 256 * j] = acc[j];
  if (t < ROW - 1024) part[(long)b * ROW + 1024 + t] = acc[4];
}

// ---------- finalize norms ----------
__global__ void k_norm(const float* __restrict__ part, float* __restrict__ invn) {
  int t = threadIdx.x;
  for (int col = t; col < ROW; col += 256) {
    float s = 0.0f;
    for (int b = 0; b < NBLK_SUM; ++b) s += part[(long)b * ROW + col];
    float nrm = fmaxf(sqrtf(s), 1e-12f);
    invn[col] = 1.0f / nrm;
  }
}

// ---------- scale pass ----------
__global__ __launch_bounds__(256) void k_scale(float4* __restrict__ out4,
                                               const float* __restrict__ invn,
                                               long n4) {
  __shared__ float inv[ROW];
  for (int i = threadIdx.x; i < ROW; i += 256) inv[i] = invn[i];
  __syncthreads();
  long stride = (long)gridDim.x * 256;
  for (long i = (long)blockIdx.x * 256 + threadIdx.x; i < n4; i += stride) {
    float4 v = out4[i];
    int col = (int)((i * 4) % ROW);
    v.x *= inv[col];
    v.y *= inv[col + 1];
    v.z *= inv[col + 2];
    v.w *= inv[col + 3];
    out4[i] = v;
  }
}

extern "C" void kernel_launch(void* const* d_in, const int* in_sizes, int n_in,
                              void* d_out, int out_size, void* d_ws, size_t ws_size,
                              hipStream_t stream) {
  const float* audio = (const float*)d_in[0];
  const float* fb = (const float*)d_in[1];
  int T = in_sizes[0];
  int nframes = 1 + T / HOP;  // center=True, pad = NFFT/2 both sides
  float* out = (float*)d_out;

  // workspace layout: part[64*1028] | invn[1028] | lohi[2*257] (int)
  float* part = (float*)d_ws;
  float* invn = part + (long)NBLK_SUM * ROW;
  int* lohi = (int*)(invn + ROW);

  k_prep<<<1, 256, 0, stream>>>(fb, lohi);
  k_fft<<<nframes, 256, 0, stream>>>(audio, fb, lohi, out, T);
  int chunks = (nframes + CHUNK - 1) / CHUNK;
  k_pcen<<<chunks, 320, 0, stream>>>(out, nframes);
  k_sumsq<<<NBLK_SUM, 256, 0, stream>>>(out, part, nframes);
  k_norm<<<1, 256, 0, stream>>>(part, invn);
  long n4 = (long)nframes * ROW / 4;
  k_scale<<<2048, 256, 0, stream>>>((float4*)out, invn, n4);
}

// Round 5
// 309.458 us; speedup vs baseline: 3.7927x; 1.8718x over previous
//
#include <hip/hip_runtime.h>
#include <math.h>

#define NFFT 512
#define HOP 128
#define NBINS 257
#define ROW 1028          // 4*257
#define CHUNK 128
#define WARM 512          // (0.975)^512 = 2.4e-6: older state negligible

// ---------- prep: sparse filterbank spans ----------
__global__ void k_prep(const float* __restrict__ fb, int* __restrict__ lohi) {
  int t = threadIdx.x;
  for (int m = t; m < NBINS; m += 256) {
    int lo = 0, hi = -1;
    for (int f = 0; f < NBINS; ++f) {
      if (fb[f * NBINS + m] != 0.0f) { if (hi < 0) lo = f; hi = f; }
    }
    lohi[m] = lo;
    lohi[NBINS + m] = hi;
  }
}

// ---------- per-frame 512-pt FFT + outputs ----------
// out layout per frame: [log_mag(257), mel(257, staged), sin(257), cos(257)]
__global__ __launch_bounds__(256) void k_fft(
    const float* __restrict__ audio, const float* __restrict__ fb,
    const int* __restrict__ lohi, float* __restrict__ out, int T) {
  __shared__ float2 bufA[NFFT];
  __shared__ float2 bufB[NFFT];
  __shared__ float2 tw[NFFT];
  __shared__ float mspec[NBINS];

  const int t = threadIdx.x;
  const int fr = blockIdx.x;

  // twiddle table tw[i] = e^{-2*pi*i* i /512}
  for (int i = t; i < NFFT; i += 256) {
    float ang = (float)(-6.283185307179586 / (double)NFFT) * (float)i;
    float s, c;
    sincosf(ang, &s, &c);
    tw[i] = make_float2(c, s);
  }
  // load frame with reflect padding
  int start = fr * HOP - NFFT / 2;
  for (int i = t; i < NFFT; i += 256) {
    int q = start + i;
    if (q < 0) q = -q;
    if (q >= T) q = 2 * T - 2 - q;
    bufA[i] = make_float2(audio[q], 0.0f);
  }
  __syncthreads();

  // 9-stage Stockham DIF, natural order in/out (verified by hand at N=4, N=8)
  float2* x = bufA;
  float2* y = bufB;
  for (int s = 0; s < 9; ++s) {
    int m = 1 << s;
    int jm = t & ~(m - 1);
    float2 c0 = x[t];
    float2 c1 = x[t + 256];
    float2 w = tw[jm];
    float2 su = make_float2(c0.x + c1.x, c0.y + c1.y);
    float2 di = make_float2(c0.x - c1.x, c0.y - c1.y);
    float2 wd = make_float2(w.x * di.x - w.y * di.y, w.x * di.y + w.y * di.x);
    y[t + jm] = su;
    y[t + jm + m] = wd;
    __syncthreads();
    float2* tmp = x; x = y; y = tmp;
  }

  long ob = (long)fr * ROW;
  for (int k = t; k < NBINS; k += 256) {
    float2 z = x[k];
    float mag, sv, cv;
    if (k == 0 || k == 256) {
      // Structural: z.y is EXACTLY 0 here (bins 0/256 route through
      // twiddle-free butterflies only). The f32 reference computes
      // sin(atan2(+0, re)) = sin(pi_f32) = -8.742278e-8 when re<0 — NOT 0.
      // F.normalize then scales that column to -1/sqrt(N_neg) ~ -7.29e-3,
      // so we must emit the same tiny values for the norm to match.
      mag = fabsf(z.x);
      sv = sinf(atan2f(0.0f, z.x));
      cv = copysignf(1.0f, z.x);
    } else {
      mag = sqrtf(z.x * z.x + z.y * z.y);
      float inv = (mag > 0.0f) ? 1.0f / mag : 0.0f;
      sv = (mag > 0.0f) ? z.y * inv : 0.0f;   // sin(angle) = im/|z|
      cv = (mag > 0.0f) ? z.x * inv : 1.0f;   // cos(angle) = re/|z|
    }
    out[ob + k] = logf(mag + 1e-9f);
    out[ob + 2 * NBINS + k] = sv;
    out[ob + 3 * NBINS + k] = cv;
    // hann spectrum via 3-tap stencil on full rect spectrum
    float2 zm = x[(k + NFFT - 1) & (NFFT - 1)];
    float2 zp = x[(k + 1) & (NFFT - 1)];
    float hr = 0.5f * z.x - 0.25f * (zm.x + zp.x);
    float hi = 0.5f * z.y - 0.25f * (zm.y + zp.y);
    mspec[k] = hr * hr + hi * hi;
  }
  __syncthreads();

  // sparse mel: stage into ch1
  for (int m = t; m < NBINS; m += 256) {
    int lo = lohi[m], hi = lohi[NBINS + m];
    float acc = 0.0f;
    for (int f = lo; f <= hi; ++f) acc = fmaf(mspec[f], fb[f * NBINS + m], acc);
    out[ob + NBINS + m] = acc;
  }
}

// ---------- fused pcen: warm-up + scan, batched loads ----------
__global__ __launch_bounds__(320) void k_pcen(float* __restrict__ out, int nframes) {
  int m = threadIdx.x;
  if (m >= NBINS) return;
  int c = blockIdx.x;
  int F0 = c * CHUNK;
  int end = min(F0 + CHUNK, nframes);
  const float SS = 0.025f, OMS = 1.0f - SS;
  const float SQ2 = sqrtf(2.0f);
  float mm = 0.0f;
  int tf = F0 - WARM;
  if (tf < 0) tf = 0;   // chunks 0..3: exact from frame 0
  // warm-up, batched 16
  for (; tf + 16 <= F0; tf += 16) {
    float xs[16];
#pragma unroll
    for (int j = 0; j < 16; ++j) xs[j] = out[(long)(tf + j) * ROW + NBINS + m];
#pragma unroll
    for (int j = 0; j < 16; ++j) mm = OMS * mm + SS * xs[j];
  }
  for (; tf < F0; ++tf) mm = OMS * mm + SS * out[(long)tf * ROW + NBINS + m];
  // scan + rewrite, batched 16
  tf = F0;
  for (; tf + 16 <= end; tf += 16) {
    float xs[16], ys[16];
#pragma unroll
    for (int j = 0; j < 16; ++j) xs[j] = out[(long)(tf + j) * ROW + NBINS + m];
#pragma unroll
    for (int j = 0; j < 16; ++j) {
      mm = OMS * mm + SS * xs[j];
      float den = expf(0.98f * logf(mm + 1e-6f));
      ys[j] = sqrtf(xs[j] / den + 2.0f) - SQ2;
    }
#pragma unroll
    for (int j = 0; j < 16; ++j) out[(long)(tf + j) * ROW + NBINS + m] = ys[j];
  }
  for (; tf < end; ++tf) {
    long idx = (long)tf * ROW + NBINS + m;
    float xv = out[idx];
    mm = OMS * mm + SS * xv;
    float den = expf(0.98f * logf(mm + 1e-6f));
    out[idx] = sqrtf(xv / den + 2.0f) - SQ2;
  }
}

// ---------- column sum-of-squares partials (deterministic, no atomics) ----------
// nblk blocks (up to 1024 -> 4 blocks/CU), 2-frame unroll -> ~10 loads in
// flight per wave. Was: 64 blocks, 1 latency per frame = 292us for a 24us read.
__global__ __launch_bounds__(256) void k_sumsq(const float* __restrict__ out,
                                               float* __restrict__ part,
                                               int nframes, int nblk) {
  int b = blockIdx.x, t = threadIdx.x;
  int per = (nframes + nblk - 1) / nblk;
  int f0 = b * per;
  int f1 = min(f0 + per, nframes);
  float acc[5] = {0.f, 0.f, 0.f, 0.f, 0.f};
  int f = f0;
  for (; f + 2 <= f1; f += 2) {
    long ba = (long)f * ROW, bb = ba + ROW;
    float va[4], vb[4];
#pragma unroll
    for (int j = 0; j < 4; ++j) va[j] = out[ba + t + 256 * j];
#pragma unroll
    for (int j = 0; j < 4; ++j) vb[j] = out[bb + t + 256 * j];
    float wa = 0.f, wb = 0.f;
    if (t < ROW - 1024) { wa = out[ba + 1024 + t]; wb = out[bb + 1024 + t]; }
#pragma unroll
    for (int j = 0; j < 4; ++j) {
      acc[j] = fmaf(va[j], va[j], acc[j]);
      acc[j] = fmaf(vb[j], vb[j], acc[j]);
    }
    acc[4] = fmaf(wa, wa, acc[4]);
    acc[4] = fmaf(wb, wb, acc[4]);
  }
  for (; f < f1; ++f) {
    long ba = (long)f * ROW;
#pragma unroll
    for (int j = 0; j < 4; ++j) {
      float v = out[ba + t + 256 * j];
      acc[j] = fmaf(v, v, acc[j]);
    }
    if (t < ROW - 1024) {
      float v = out[ba + 1024 + t];
      acc[4] = fmaf(v, v, acc[4]);
    }
  }
#pragma unroll
  for (int j = 0; j < 4; ++j) part[(long)b * ROW + t + 256 * j] = acc[j];
  if (t < ROW - 1024) part[(long)b * ROW + 1024 + t] = acc[4];
}

// ---------- finalize norms: one block per column, LDS tree (deterministic) ----------
__global__ __launch_bounds__(256) void k_norm(const float* __restrict__ part,
                                              float* __restrict__ invn, int nblk) {
  __shared__ float red[256];
  int c = blockIdx.x, t = threadIdx.x;
  float s = 0.0f;
  for (int b = t; b < nblk; b += 256) s += part[(long)b * ROW + c];
  red[t] = s;
  __syncthreads();
  for (int o = 128; o > 0; o >>= 1) {
    if (t < o) red[t] += red[t + o];
    __syncthreads();
  }
  if (t == 0) invn[c] = 1.0f / fmaxf(sqrtf(red[0]), 1e-12f);
}

// ---------- scale pass ----------
__global__ __launch_bounds__(256) void k_scale(float4* __restrict__ out4,
                                               const float* __restrict__ invn,
                                               long n4) {
  __shared__ float inv[ROW];
  for (int i = threadIdx.x; i < ROW; i += 256) inv[i] = invn[i];
  __syncthreads();
  long stride = (long)gridDim.x * 256;
  for (long i = (long)blockIdx.x * 256 + threadIdx.x; i < n4; i += stride) {
    float4 v = out4[i];
    int col = (int)((i * 4) % ROW);
    v.x *= inv[col];
    v.y *= inv[col + 1];
    v.z *= inv[col + 2];
    v.w *= inv[col + 3];
    out4[i] = v;
  }
}

extern "C" void kernel_launch(void* const* d_in, const int* in_sizes, int n_in,
                              void* d_out, int out_size, void* d_ws, size_t ws_size,
                              hipStream_t stream) {
  const float* audio = (const float*)d_in[0];
  const float* fb = (const float*)d_in[1];
  int T = in_sizes[0];
  int nframes = 1 + T / HOP;  // center=True, pad = NFFT/2 both sides
  float* out = (float*)d_out;

  // choose sumsq partial count from available workspace (deterministic: ws_size fixed)
  long avail = (long)(ws_size / 4) - ROW - 600;  // floats for part[]; invn + lohi after
  int nblk = 1024;
  while (nblk > 64 && (long)nblk * ROW > avail) nblk >>= 1;

  // workspace layout: part[nblk*1028] | invn[1028] | lohi[2*257] (int)
  float* part = (float*)d_ws;
  float* invn = part + (long)nblk * ROW;
  int* lohi = (int*)(invn + ROW);

  k_prep<<<1, 256, 0, stream>>>(fb, lohi);
  k_fft<<<nframes, 256, 0, stream>>>(audio, fb, lohi, out, T);
  int chunks = (nframes + CHUNK - 1) / CHUNK;
  k_pcen<<<chunks, 320, 0, stream>>>(out, nframes);
  k_sumsq<<<nblk, 256, 0, stream>>>(out, part, nframes, nblk);
  k_norm<<<ROW, 256, 0, stream>>>(part, invn, nblk);
  long n4 = (long)nframes * ROW / 4;
  k_scale<<<2048, 256, 0, stream>>>((float4*)out, invn, n4);
}

// Round 6
// 272.279 us; speedup vs baseline: 4.3106x; 1.1365x over previous
//
#include <hip/hip_runtime.h>
#include <math.h>

#define NFFT 512
#define HOP 128
#define NBINS 257
#define ROW 1028          // 4*257
#define CHUNK 128
#define WARM 512          // (0.975)^512 = 2.4e-6: older state negligible

// ---------- prep: twiddle table (once!) + sparse filterbank spans ----------
__global__ void k_prep(const float* __restrict__ fb, int* __restrict__ lohi,
                       float2* __restrict__ twg) {
  int t = threadIdx.x;
  for (int i = t; i < NFFT; i += 256) {
    double ang = -6.283185307179586476925286766559 * (double)i / (double)NFFT;
    twg[i] = make_float2((float)cos(ang), (float)sin(ang));
  }
  for (int m = t; m < NBINS; m += 256) {
    int lo = 0, hi = -1;
    for (int f = 0; f < NBINS; ++f) {
      if (fb[f * NBINS + m] != 0.0f) { if (hi < 0) lo = f; hi = f; }
    }
    lohi[m] = lo;
    lohi[NBINS + m] = hi;
  }
}

// ---------- per-bin epilogue ----------
__device__ __forceinline__ void epilogue_bin(const float2* __restrict__ S,
                                             float* __restrict__ mspec,
                                             float* __restrict__ out, long ob,
                                             int k) {
  float2 z = S[k];
  float mag, sv, cv;
  if (k == 0 || k == 256) {
    // z.y is EXACTLY 0 here (unpack cancels identically at k==m). The f32
    // reference computes sin(atan2(+0, re)) = sin(pi_f32) = -8.742278e-8 when
    // re<0 — NOT 0. F.normalize scales that column to -1/sqrt(N_neg), so we
    // must emit the same tiny values for the norm to match.
    mag = fabsf(z.x);
    sv = sinf(atan2f(0.0f, z.x));
    cv = copysignf(1.0f, z.x);
  } else {
    mag = sqrtf(z.x * z.x + z.y * z.y);
    float inv = (mag > 0.0f) ? 1.0f / mag : 0.0f;
    sv = (mag > 0.0f) ? z.y * inv : 0.0f;   // sin(angle) = im/|z|
    cv = (mag > 0.0f) ? z.x * inv : 1.0f;   // cos(angle) = re/|z|
  }
  out[ob + k] = logf(mag + 1e-9f);
  out[ob + 2 * NBINS + k] = sv;
  out[ob + 3 * NBINS + k] = cv;
  // hann spectrum via 3-tap stencil; S holds X[0..257], X[-1] = conj(X[1])
  float2 zm = (k == 0) ? make_float2(S[1].x, -S[1].y) : S[k - 1];
  float2 zp = S[k + 1];
  float hr = 0.5f * z.x - 0.25f * (zm.x + zp.x);
  float hi = 0.5f * z.y - 0.25f * (zm.y + zp.y);
  mspec[k] = hr * hr + hi * hi;
}

// ---------- two frames per block: one complex FFT (two-for-one real trick) ----------
// out layout per frame: [log_mag(257), mel(257, staged), sin(257), cos(257)]
__global__ __launch_bounds__(256) void k_fft(
    const float* __restrict__ audio, const float* __restrict__ fb,
    const int* __restrict__ lohi, const float2* __restrict__ twg,
    float* __restrict__ out, int T, int nframes) {
  __shared__ float2 bufA[NFFT];
  __shared__ float2 bufB[NFFT];
  __shared__ float2 twL[NFFT];   // twiddles during FFT; reused as X2 after
  __shared__ float mspecA[NBINS];
  __shared__ float mspecB[NBINS];

  const int t = threadIdx.x;
  const int fr0 = blockIdx.x * 2;
  const int fr1 = fr0 + 1;
  const bool has1 = fr1 < nframes;

  for (int i = t; i < NFFT; i += 256) twL[i] = twg[i];
  // load both frames with reflect padding: z = frame0 + i*frame1
  int s0 = fr0 * HOP - NFFT / 2;
  int s1 = s0 + HOP;
  for (int i = t; i < NFFT; i += 256) {
    int q0 = s0 + i;
    if (q0 < 0) q0 = -q0;
    if (q0 >= T) q0 = 2 * T - 2 - q0;
    int q1 = s1 + i;
    if (q1 < 0) q1 = -q1;
    if (q1 >= T) q1 = 2 * T - 2 - q1;
    float b = has1 ? audio[q1] : 0.0f;
    bufA[i] = make_float2(audio[q0], b);
  }
  __syncthreads();

  // 9-stage Stockham DIF, natural order in/out (verified by hand at N=4, N=8)
  float2* x = bufA;
  float2* y = bufB;
  for (int s = 0; s < 9; ++s) {
    int m = 1 << s;
    int jm = t & ~(m - 1);
    float2 c0 = x[t];
    float2 c1 = x[t + 256];
    float2 w = twL[jm];
    float2 su = make_float2(c0.x + c1.x, c0.y + c1.y);
    float2 di = make_float2(c0.x - c1.x, c0.y - c1.y);
    float2 wd = make_float2(w.x * di.x - w.y * di.y, w.x * di.y + w.y * di.x);
    y[t + jm] = su;
    y[t + jm + m] = wd;
    __syncthreads();
    float2* tmp = x; x = y; y = tmp;
  }

  // unpack: X1[k] = (Z[k]+conj(Z[-k]))/2 -> y ; X2[k] = (Z[k]-conj(Z[-k]))/2i -> twL
  // (verified: N=4, a=delta, b=shifted delta -> A=[1,1,1,1], B=[1,-i,-1,i])
  for (int k = t; k < 258; k += 256) {
    int m2 = (NFFT - k) & (NFFT - 1);
    float2 Zk = x[k];
    float2 Zm = x[m2];
    y[k] = make_float2(0.5f * (Zk.x + Zm.x), 0.5f * (Zk.y - Zm.y));
    twL[k] = make_float2(0.5f * (Zk.y + Zm.y), 0.5f * (Zm.x - Zk.x));
  }
  __syncthreads();

  long ob0 = (long)fr0 * ROW;
  long ob1 = (long)fr1 * ROW;
  for (int k = t; k < NBINS; k += 256) {
    epilogue_bin(y, mspecA, out, ob0, k);
    if (has1) epilogue_bin(twL, mspecB, out, ob1, k);
  }
  __syncthreads();

  // sparse mel for both frames: fb taps amortized
  for (int m = t; m < NBINS; m += 256) {
    int lo = lohi[m], hi = lohi[NBINS + m];
    float acc0 = 0.0f, acc1 = 0.0f;
    for (int f = lo; f <= hi; ++f) {
      float w = fb[f * NBINS + m];
      acc0 = fmaf(mspecA[f], w, acc0);
      acc1 = fmaf(mspecB[f], w, acc1);
    }
    out[ob0 + NBINS + m] = acc0;
    if (has1) out[ob1 + NBINS + m] = acc1;
  }
}

// ---------- fused pcen: warm-up + scan, batched loads ----------
__global__ __launch_bounds__(320) void k_pcen(float* __restrict__ out, int nframes) {
  int m = threadIdx.x;
  if (m >= NBINS) return;
  int c = blockIdx.x;
  int F0 = c * CHUNK;
  int end = min(F0 + CHUNK, nframes);
  const float SS = 0.025f, OMS = 1.0f - SS;
  const float SQ2 = sqrtf(2.0f);
  float mm = 0.0f;
  int tf = F0 - WARM;
  if (tf < 0) tf = 0;   // chunks 0..3: exact from frame 0
  // warm-up, batched 16
  for (; tf + 16 <= F0; tf += 16) {
    float xs[16];
#pragma unroll
    for (int j = 0; j < 16; ++j) xs[j] = out[(long)(tf + j) * ROW + NBINS + m];
#pragma unroll
    for (int j = 0; j < 16; ++j) mm = OMS * mm + SS * xs[j];
  }
  for (; tf < F0; ++tf) mm = OMS * mm + SS * out[(long)tf * ROW + NBINS + m];
  // scan + rewrite, batched 16
  tf = F0;
  for (; tf + 16 <= end; tf += 16) {
    float xs[16], ys[16];
#pragma unroll
    for (int j = 0; j < 16; ++j) xs[j] = out[(long)(tf + j) * ROW + NBINS + m];
#pragma unroll
    for (int j = 0; j < 16; ++j) {
      mm = OMS * mm + SS * xs[j];
      float den = expf(0.98f * logf(mm + 1e-6f));
      ys[j] = sqrtf(xs[j] / den + 2.0f) - SQ2;
    }
#pragma unroll
    for (int j = 0; j < 16; ++j) out[(long)(tf + j) * ROW + NBINS + m] = ys[j];
  }
  for (; tf < end; ++tf) {
    long idx = (long)tf * ROW + NBINS + m;
    float xv = out[idx];
    mm = OMS * mm + SS * xv;
    float den = expf(0.98f * logf(mm + 1e-6f));
    out[idx] = sqrtf(xv / den + 2.0f) - SQ2;
  }
}

// ---------- column sum-of-squares partials (deterministic, no atomics) ----------
__global__ __launch_bounds__(256) void k_sumsq(const float* __restrict__ out,
                                               float* __restrict__ part,
                                               int nframes, int nblk) {
  int b = blockIdx.x, t = threadIdx.x;
  int per = (nframes + nblk - 1) / nblk;
  int f0 = b * per;
  int f1 = min(f0 + per, nframes);
  float acc[5] = {0.f, 0.f, 0.f, 0.f, 0.f};
  int f = f0;
  for (; f + 2 <= f1; f += 2) {
    long ba = (long)f * ROW, bb = ba + ROW;
    float va[4], vb[4];
#pragma unroll
    for (int j = 0; j < 4; ++j) va[j] = out[ba + t + 256 * j];
#pragma unroll
    for (int j = 0; j < 4; ++j) vb[j] = out[bb + t + 256 * j];
    float wa = 0.f, wb = 0.f;
    if (t < ROW - 1024) { wa = out[ba + 1024 + t]; wb = out[bb + 1024 + t]; }
#pragma unroll
    for (int j = 0; j < 4; ++j) {
      acc[j] = fmaf(va[j], va[j], acc[j]);
      acc[j] = fmaf(vb[j], vb[j], acc[j]);
    }
    acc[4] = fmaf(wa, wa, acc[4]);
    acc[4] = fmaf(wb, wb, acc[4]);
  }
  for (; f < f1; ++f) {
    long ba = (long)f * ROW;
#pragma unroll
    for (int j = 0; j < 4; ++j) {
      float v = out[ba + t + 256 * j];
      acc[j] = fmaf(v, v, acc[j]);
    }
    if (t < ROW - 1024) {
      float v = out[ba + 1024 + t];
      acc[4] = fmaf(v, v, acc[4]);
    }
  }
#pragma unroll
  for (int j = 0; j < 4; ++j) part[(long)b * ROW + t + 256 * j] = acc[j];
  if (t < ROW - 1024) part[(long)b * ROW + 1024 + t] = acc[4];
}

// ---------- finalize norms: one block per column, LDS tree (deterministic) ----------
__global__ __launch_bounds__(256) void k_norm(const float* __restrict__ part,
                                              float* __restrict__ invn, int nblk) {
  __shared__ float red[256];
  int c = blockIdx.x, t = threadIdx.x;
  float s = 0.0f;
  for (int b = t; b < nblk; b += 256) s += part[(long)b * ROW + c];
  red[t] = s;
  __syncthreads();
  for (int o = 128; o > 0; o >>= 1) {
    if (t < o) red[t] += red[t + o];
    __syncthreads();
  }
  if (t == 0) invn[c] = 1.0f / fmaxf(sqrtf(red[0]), 1e-12f);
}

// ---------- scale pass ----------
__global__ __launch_bounds__(256) void k_scale(float4* __restrict__ out4,
                                               const float* __restrict__ invn,
                                               long n4) {
  __shared__ float inv[ROW];
  for (int i = threadIdx.x; i < ROW; i += 256) inv[i] = invn[i];
  __syncthreads();
  long stride = (long)gridDim.x * 256;
  for (long i = (long)blockIdx.x * 256 + threadIdx.x; i < n4; i += stride) {
    float4 v = out4[i];
    int col = (int)((i * 4) % ROW);
    v.x *= inv[col];
    v.y *= inv[col + 1];
    v.z *= inv[col + 2];
    v.w *= inv[col + 3];
    out4[i] = v;
  }
}

extern "C" void kernel_launch(void* const* d_in, const int* in_sizes, int n_in,
                              void* d_out, int out_size, void* d_ws, size_t ws_size,
                              hipStream_t stream) {
  const float* audio = (const float*)d_in[0];
  const float* fb = (const float*)d_in[1];
  int T = in_sizes[0];
  int nframes = 1 + T / HOP;  // center=True, pad = NFFT/2 both sides
  float* out = (float*)d_out;

  // choose sumsq partial count from available workspace (deterministic: ws_size fixed)
  long avail = (long)(ws_size / 4) - 1024 - ROW - 600;
  int nblk = 1024;
  while (nblk > 64 && (long)nblk * ROW > avail) nblk >>= 1;

  // workspace layout: twg[512] float2 | part[nblk*1028] | invn[1028] | lohi[2*257] (int)
  float2* twg = (float2*)d_ws;
  float* part = (float*)d_ws + 1024;
  float* invn = part + (long)nblk * ROW;
  int* lohi = (int*)(invn + ROW);

  k_prep<<<1, 256, 0, stream>>>(fb, lohi, twg);
  int npairs = (nframes + 1) / 2;
  k_fft<<<npairs, 256, 0, stream>>>(audio, fb, lohi, twg, out, T, nframes);
  int chunks = (nframes + CHUNK - 1) / CHUNK;
  k_pcen<<<chunks, 320, 0, stream>>>(out, nframes);
  k_sumsq<<<nblk, 256, 0, stream>>>(out, part, nframes, nblk);
  k_norm<<<ROW, 256, 0, stream>>>(part, invn, nblk);
  long n4 = (long)nframes * ROW / 4;
  k_scale<<<2048, 256, 0, stream>>>((float4*)out, invn, n4);
}